// Round 1
// baseline (7383.450 us; speedup 1.0000x reference)
//
#include <hip/hip_runtime.h>
#include <hip/hip_bf16.h>
#include <math.h>

#define S_LEN 2048
#define D_MODEL 2048
#define D_HEAD 64
#define Q_HEADS 32
#define KV_HEADS 8

// ---------------------------------------------------------------------------
// C[m,n] = sum_k A[m,k] * B[n,k] + bias[n]   (B row-major [N,K], i.e. A @ B^T)
// BM=BN=64, BK=16, 256 threads, 4x4 microtile per thread.
// LDS padded to stride 17 (odd) so B-tile reads are 2-way (free) instead of
// 16-way bank conflicts; A-tile reads land on 4 distinct banks per wave.
// ---------------------------------------------------------------------------
__global__ __launch_bounds__(256) void gemm_bt(
    const float* __restrict__ A, const float* __restrict__ B,
    const float* __restrict__ bias, float* __restrict__ C,
    int M, int N, int K) {
  __shared__ float As[64][17];
  __shared__ float Bs[64][17];
  const int bm = blockIdx.y * 64;
  const int bn = blockIdx.x * 64;
  const int tid = threadIdx.x;
  const int tx = tid & 15;        // 0..15  -> n
  const int ty = tid >> 4;        // 0..15  -> m
  float acc[4][4] = {};

  const int lrow = tid >> 2;        // 0..63
  const int lcol = (tid & 3) * 4;   // 0,4,8,12

  for (int k0 = 0; k0 < K; k0 += 16) {
    float4 av = *(const float4*)&A[(long)(bm + lrow) * K + k0 + lcol];
    float4 bv = *(const float4*)&B[(long)(bn + lrow) * K + k0 + lcol];
    // scalar LDS stores (padded stride 17 breaks float4 alignment)
    As[lrow][lcol + 0] = av.x; As[lrow][lcol + 1] = av.y;
    As[lrow][lcol + 2] = av.z; As[lrow][lcol + 3] = av.w;
    Bs[lrow][lcol + 0] = bv.x; Bs[lrow][lcol + 1] = bv.y;
    Bs[lrow][lcol + 2] = bv.z; Bs[lrow][lcol + 3] = bv.w;
    __syncthreads();
#pragma unroll
    for (int k = 0; k < 16; ++k) {
      float a[4], b[4];
#pragma unroll
      for (int i = 0; i < 4; ++i) a[i] = As[ty * 4 + i][k];
#pragma unroll
      for (int j = 0; j < 4; ++j) b[j] = Bs[tx * 4 + j][k];
#pragma unroll
      for (int i = 0; i < 4; ++i)
#pragma unroll
        for (int j = 0; j < 4; ++j) acc[i][j] += a[i] * b[j];
    }
    __syncthreads();
  }

#pragma unroll
  for (int i = 0; i < 4; ++i) {
    const int m = bm + ty * 4 + i;
#pragma unroll
    for (int j = 0; j < 4; ++j) {
      const int n = bn + tx * 4 + j;
      C[(long)m * N + n] = acc[i][j] + bias[n];
    }
  }
}

// ---------------------------------------------------------------------------
// RoPE, interleaved pairs. X layout [S, rowstride], heads at cols h*64.
// One block per sequence position; nheads*32 threads.
// Angles in double: reference computes freq/theta in fp32 but numpy's pow and
// large-angle sincos are near-exact; double here keeps us ~1e-7 of the f32
// reference values instead of __powf's ~1e-5 relative drift (x2047 rad).
// ---------------------------------------------------------------------------
__global__ void rope_kernel(float* __restrict__ X, int rowstride) {
  const int s = blockIdx.x;
  const int tid = threadIdx.x;
  const int h = tid >> 5;        // head
  const int j = tid & 31;        // pair index
  const double e = (2.0 * j) / 64.0;
  const double freq = pow(10000.0, -e);
  const double theta = (double)s * freq;
  double sd, cd;
  sincos(theta, &sd, &cd);
  const float cs = (float)cd, sn = (float)sd;
  float* p = &X[(long)s * rowstride + h * 64 + 2 * j];
  const float x1 = p[0], x2 = p[1];
  p[0] = x1 * cs - x2 * sn;
  p[1] = x1 * sn + x2 * cs;
}

// ---------------------------------------------------------------------------
// Attention: one block per (query row, head). Two-pass softmax in LDS.
// KV layout: [S, 1024], K at cols [kvh*64 .. ), V at cols [512 + kvh*64 .. ).
// ---------------------------------------------------------------------------
__global__ __launch_bounds__(256) void attn_kernel(
    const float* __restrict__ Q, const float* __restrict__ KV,
    float* __restrict__ O) {
  const int q = blockIdx.x;
  const int h = blockIdx.y;
  const int kvh = h >> 2;   // g = Q_HEADS / KV_HEADS = 4
  const int tid = threadIdx.x;

  __shared__ float qs[D_HEAD];
  __shared__ float sc[S_LEN];
  __shared__ float red[256];

  if (tid < D_HEAD) qs[tid] = Q[(long)q * D_MODEL + h * 64 + tid];
  __syncthreads();

  // scores
  for (int k = tid; k < S_LEN; k += 256) {
    const float* krow = &KV[(long)k * 1024 + kvh * 64];
    float d = 0.f;
#pragma unroll
    for (int i = 0; i < D_HEAD; ++i) d += qs[i] * krow[i];
    sc[k] = d * 0.125f;  // 1/sqrt(64)
  }
  __syncthreads();

  // block max
  float m = -INFINITY;
  for (int k = tid; k < S_LEN; k += 256) m = fmaxf(m, sc[k]);
  red[tid] = m;
  __syncthreads();
  for (int s2 = 128; s2 > 0; s2 >>= 1) {
    if (tid < s2) red[tid] = fmaxf(red[tid], red[tid + s2]);
    __syncthreads();
  }
  m = red[0];
  __syncthreads();

  // exp + sum
  float l = 0.f;
  for (int k = tid; k < S_LEN; k += 256) {
    const float e = __expf(sc[k] - m);
    sc[k] = e;
    l += e;
  }
  red[tid] = l;
  __syncthreads();
  for (int s2 = 128; s2 > 0; s2 >>= 1) {
    if (tid < s2) red[tid] += red[tid + s2];
    __syncthreads();
  }
  const float linv = 1.f / red[0];
  __syncthreads();

  // P @ V : thread (d = tid%64, c = tid/64) sums keys [c*512, (c+1)*512)
  const int d = tid & 63;
  const int c = tid >> 6;
  float acc = 0.f;
  const int kbeg = c * 512, kend = kbeg + 512;
  for (int k = kbeg; k < kend; ++k)
    acc += sc[k] * KV[(long)k * 1024 + 512 + kvh * 64 + d];
  red[tid] = acc;
  __syncthreads();
  if (tid < 64) {
    const float o = red[d] + red[64 + d] + red[128 + d] + red[192 + d];
    O[(long)q * D_MODEL + h * 64 + d] = o * linv;
  }
}

// ---------------------------------------------------------------------------
extern "C" void kernel_launch(void* const* d_in, const int* in_sizes, int n_in,
                              void* d_out, int out_size, void* d_ws, size_t ws_size,
                              hipStream_t stream) {
  const float* x     = (const float*)d_in[0];  // [1,2048,2048]
  const float* W_q   = (const float*)d_in[1];  // [2048,2048]
  const float* b_q   = (const float*)d_in[2];  // [2048]
  const float* W_kv  = (const float*)d_in[3];  // [1024,2048]
  const float* b_kv  = (const float*)d_in[4];  // [1024]
  const float* W_out = (const float*)d_in[5];  // [2048,2048]
  const float* b_out = (const float*)d_in[6];  // [2048]
  float* out = (float*)d_out;                  // [1,2048,2048]

  float* Qbuf  = (float*)d_ws;                          // 2048*2048
  float* KVbuf = Qbuf + (long)S_LEN * D_MODEL;          // 2048*1024
  float* Abuf  = KVbuf + (long)S_LEN * 1024;            // 2048*2048

  // Q projection: [2048,2048] = x @ W_q^T + b_q
  gemm_bt<<<dim3(D_MODEL / 64, S_LEN / 64), 256, 0, stream>>>(
      x, W_q, b_q, Qbuf, S_LEN, D_MODEL, D_MODEL);
  // KV projection: [2048,1024] = x @ W_kv^T + b_kv
  gemm_bt<<<dim3(1024 / 64, S_LEN / 64), 256, 0, stream>>>(
      x, W_kv, b_kv, KVbuf, S_LEN, 1024, D_MODEL);

  // RoPE on Q (32 heads) and K (first 512 cols of KV, 8 heads)
  rope_kernel<<<S_LEN, Q_HEADS * 32, 0, stream>>>(Qbuf, D_MODEL);
  rope_kernel<<<S_LEN, KV_HEADS * 32, 0, stream>>>(KVbuf, 1024);

  // attention
  attn_kernel<<<dim3(S_LEN, Q_HEADS), 256, 0, stream>>>(Qbuf, KVbuf, Abuf);

  // out projection
  gemm_bt<<<dim3(D_MODEL / 64, S_LEN / 64), 256, 0, stream>>>(
      Abuf, W_out, b_out, out, S_LEN, D_MODEL, D_MODEL);
}

// Round 2
// 1499.239 us; speedup vs baseline: 4.9248x; 4.9248x over previous
//
#include <hip/hip_runtime.h>
#include <hip/hip_bf16.h>
#include <math.h>

#define S_LEN 2048
#define D_MODEL 2048
#define D_HEAD 64
#define Q_HEADS 32
#define KV_HEADS 8

// ---------------------------------------------------------------------------
// C[m,n] = sum_k A[m,k] * B[n,k] + bias[n]   (B row-major [N,K], i.e. A @ B^T)
// BM=BN=64, BK=16, 256 threads, 4x4 microtile per thread.
// ---------------------------------------------------------------------------
__global__ __launch_bounds__(256) void gemm_bt(
    const float* __restrict__ A, const float* __restrict__ B,
    const float* __restrict__ bias, float* __restrict__ C,
    int M, int N, int K) {
  __shared__ float As[64][17];
  __shared__ float Bs[64][17];
  const int bm = blockIdx.y * 64;
  const int bn = blockIdx.x * 64;
  const int tid = threadIdx.x;
  const int tx = tid & 15;        // 0..15  -> n
  const int ty = tid >> 4;        // 0..15  -> m
  float acc[4][4] = {};

  const int lrow = tid >> 2;        // 0..63
  const int lcol = (tid & 3) * 4;   // 0,4,8,12

  for (int k0 = 0; k0 < K; k0 += 16) {
    float4 av = *(const float4*)&A[(long)(bm + lrow) * K + k0 + lcol];
    float4 bv = *(const float4*)&B[(long)(bn + lrow) * K + k0 + lcol];
    As[lrow][lcol + 0] = av.x; As[lrow][lcol + 1] = av.y;
    As[lrow][lcol + 2] = av.z; As[lrow][lcol + 3] = av.w;
    Bs[lrow][lcol + 0] = bv.x; Bs[lrow][lcol + 1] = bv.y;
    Bs[lrow][lcol + 2] = bv.z; Bs[lrow][lcol + 3] = bv.w;
    __syncthreads();
#pragma unroll
    for (int k = 0; k < 16; ++k) {
      float a[4], b[4];
#pragma unroll
      for (int i = 0; i < 4; ++i) a[i] = As[ty * 4 + i][k];
#pragma unroll
      for (int j = 0; j < 4; ++j) b[j] = Bs[tx * 4 + j][k];
#pragma unroll
      for (int i = 0; i < 4; ++i)
#pragma unroll
        for (int j = 0; j < 4; ++j) acc[i][j] += a[i] * b[j];
    }
    __syncthreads();
  }

#pragma unroll
  for (int i = 0; i < 4; ++i) {
    const int m = bm + ty * 4 + i;
#pragma unroll
    for (int j = 0; j < 4; ++j) {
      const int n = bn + tx * 4 + j;
      C[(long)m * N + n] = acc[i][j] + bias[n];
    }
  }
}

// ---------------------------------------------------------------------------
// RoPE, interleaved pairs (double-precision angles).
// ---------------------------------------------------------------------------
__global__ void rope_kernel(float* __restrict__ X, int rowstride) {
  const int s = blockIdx.x;
  const int tid = threadIdx.x;
  const int h = tid >> 5;
  const int j = tid & 31;
  const double e = (2.0 * j) / 64.0;
  const double freq = pow(10000.0, -e);
  const double theta = (double)s * freq;
  double sd, cd;
  sincos(theta, &sd, &cd);
  const float cs = (float)cd, sn = (float)sd;
  float* p = &X[(long)s * rowstride + h * 64 + 2 * j];
  const float x1 = p[0], x2 = p[1];
  p[0] = x1 * cs - x2 * sn;
  p[1] = x1 * sn + x2 * cs;
}

// ---------------------------------------------------------------------------
// Flash attention, fp32 VALU. Grid (S/64, Q_HEADS), 256 threads.
// Per block: 64 q-rows x one head. Loop over 32 K-tiles of 64 keys.
// LDS layouts (stride 68 floats = 272 B, 16B-aligned rows):
//   Qt[d][q]  - Q-tile transposed, pre-scaled by 1/8, staged once
//   Kt[d][key]- K-tile transposed (S-phase reads are b128, tx-spread, 2-way)
//   Vs[key][d]- V-tile natural
//   Ps[q][k]  - exp'd probabilities (PV-phase reads broadcast over tx)
// Online softmax: m,l per q-row in registers, replicated across tx lanes
// (shfl_xor 1/2/4/8 reduces within the 16-lane tx group of one wave).
// ---------------------------------------------------------------------------
__global__ __launch_bounds__(256) void flash_attn(
    const float* __restrict__ Q, const float* __restrict__ KV,
    float* __restrict__ O) {
  const int qt = blockIdx.x;
  const int h  = blockIdx.y;
  const int kvh = h >> 2;          // 4 q-heads per kv-head
  const int tid = threadIdx.x;
  const int tx = tid & 15;
  const int ty = tid >> 4;

  __shared__ float Qt[64][68];
  __shared__ float Kt[64][68];
  __shared__ float Vs[64][68];
  __shared__ float Ps[64][68];

  const int srow = tid >> 2;        // 0..63
  const int scol = (tid & 3) * 4;   // 0,4,8,12  (4 lanes cover 16 consec floats)

  // ---- stage Q transposed, pre-scaled by 1/sqrt(64) ----
  {
    const float* qg = &Q[(long)(qt * 64 + srow) * D_MODEL + h * 64];
#pragma unroll
    for (int c2 = 0; c2 < 4; ++c2) {
      const int c = scol + 16 * c2;
      float4 v = *(const float4*)&qg[c];
      Qt[c + 0][srow] = v.x * 0.125f;
      Qt[c + 1][srow] = v.y * 0.125f;
      Qt[c + 2][srow] = v.z * 0.125f;
      Qt[c + 3][srow] = v.w * 0.125f;
    }
  }

  float m[4], l[4], o[4][4];
#pragma unroll
  for (int i = 0; i < 4; ++i) {
    m[i] = -INFINITY; l[i] = 0.f;
#pragma unroll
    for (int j = 0; j < 4; ++j) o[i][j] = 0.f;
  }

  for (int t = 0; t < 32; ++t) {
    __syncthreads();   // prior PV reads of Kt/Vs done
    // ---- stage K (transposed) and V (natural) ----
    {
      const float* kg = &KV[(long)(t * 64 + srow) * 1024 + kvh * 64];
#pragma unroll
      for (int c2 = 0; c2 < 4; ++c2) {
        const int c = scol + 16 * c2;
        float4 kv4 = *(const float4*)&kg[c];
        Kt[c + 0][srow] = kv4.x;
        Kt[c + 1][srow] = kv4.y;
        Kt[c + 2][srow] = kv4.z;
        Kt[c + 3][srow] = kv4.w;
        float4 vv4 = *(const float4*)&kg[512 + c];
        *(float4*)&Vs[srow][c] = vv4;
      }
    }
    __syncthreads();

    // ---- S = (Q/8) . K^T : 4x4 microtile over [q=4ty+i][key=4tx+j] ----
    float s[4][4] = {};
#pragma unroll 8
    for (int k = 0; k < 64; ++k) {
      float4 qv = *(const float4*)&Qt[k][ty * 4];
      float4 kv = *(const float4*)&Kt[k][tx * 4];
      const float qa[4] = {qv.x, qv.y, qv.z, qv.w};
      const float kb[4] = {kv.x, kv.y, kv.z, kv.w};
#pragma unroll
      for (int i = 0; i < 4; ++i)
#pragma unroll
        for (int j = 0; j < 4; ++j) s[i][j] += qa[i] * kb[j];
    }

    // ---- online softmax per q-row ----
#pragma unroll
    for (int i = 0; i < 4; ++i) {
      float rm = fmaxf(fmaxf(s[i][0], s[i][1]), fmaxf(s[i][2], s[i][3]));
      rm = fmaxf(rm, __shfl_xor(rm, 1));
      rm = fmaxf(rm, __shfl_xor(rm, 2));
      rm = fmaxf(rm, __shfl_xor(rm, 4));
      rm = fmaxf(rm, __shfl_xor(rm, 8));
      const float mnew = fmaxf(m[i], rm);
      const float alpha = __expf(m[i] - mnew);
      float rs = 0.f;
#pragma unroll
      for (int j = 0; j < 4; ++j) {
        s[i][j] = __expf(s[i][j] - mnew);
        rs += s[i][j];
      }
      rs += __shfl_xor(rs, 1);
      rs += __shfl_xor(rs, 2);
      rs += __shfl_xor(rs, 4);
      rs += __shfl_xor(rs, 8);
      l[i] = l[i] * alpha + rs;
      m[i] = mnew;
#pragma unroll
      for (int j = 0; j < 4; ++j) o[i][j] *= alpha;
      *(float4*)&Ps[ty * 4 + i][tx * 4] =
          make_float4(s[i][0], s[i][1], s[i][2], s[i][3]);
    }
    __syncthreads();   // Ps visible to all (and paranoia vs same-wave RAW)

    // ---- O += P . V : o[i][j], j = d-col tx*4+j ----
#pragma unroll 4
    for (int k0 = 0; k0 < 64; k0 += 4) {
      float p[4][4], v[4][4];
#pragma unroll
      for (int i = 0; i < 4; ++i) {
        float4 t4 = *(const float4*)&Ps[ty * 4 + i][k0];
        p[i][0] = t4.x; p[i][1] = t4.y; p[i][2] = t4.z; p[i][3] = t4.w;
      }
#pragma unroll
      for (int kk = 0; kk < 4; ++kk) {
        float4 t4 = *(const float4*)&Vs[k0 + kk][tx * 4];
        v[kk][0] = t4.x; v[kk][1] = t4.y; v[kk][2] = t4.z; v[kk][3] = t4.w;
      }
#pragma unroll
      for (int i = 0; i < 4; ++i)
#pragma unroll
        for (int kk = 0; kk < 4; ++kk)
#pragma unroll
          for (int j = 0; j < 4; ++j) o[i][j] += p[i][kk] * v[kk][j];
    }
  }

  // ---- epilogue: O / l ----
#pragma unroll
  for (int i = 0; i < 4; ++i) {
    const float inv = 1.f / l[i];
    float4 r = make_float4(o[i][0] * inv, o[i][1] * inv,
                           o[i][2] * inv, o[i][3] * inv);
    *(float4*)&O[(long)(qt * 64 + ty * 4 + i) * D_MODEL + h * 64 + tx * 4] = r;
  }
}

// ---------------------------------------------------------------------------
extern "C" void kernel_launch(void* const* d_in, const int* in_sizes, int n_in,
                              void* d_out, int out_size, void* d_ws, size_t ws_size,
                              hipStream_t stream) {
  const float* x     = (const float*)d_in[0];
  const float* W_q   = (const float*)d_in[1];
  const float* b_q   = (const float*)d_in[2];
  const float* W_kv  = (const float*)d_in[3];
  const float* b_kv  = (const float*)d_in[4];
  const float* W_out = (const float*)d_in[5];
  const float* b_out = (const float*)d_in[6];
  float* out = (float*)d_out;

  float* Qbuf  = (float*)d_ws;                          // 2048*2048
  float* KVbuf = Qbuf + (long)S_LEN * D_MODEL;          // 2048*1024
  float* Abuf  = KVbuf + (long)S_LEN * 1024;            // 2048*2048

  gemm_bt<<<dim3(D_MODEL / 64, S_LEN / 64), 256, 0, stream>>>(
      x, W_q, b_q, Qbuf, S_LEN, D_MODEL, D_MODEL);
  gemm_bt<<<dim3(1024 / 64, S_LEN / 64), 256, 0, stream>>>(
      x, W_kv, b_kv, KVbuf, S_LEN, 1024, D_MODEL);

  rope_kernel<<<S_LEN, Q_HEADS * 32, 0, stream>>>(Qbuf, D_MODEL);
  rope_kernel<<<S_LEN, KV_HEADS * 32, 0, stream>>>(KVbuf, 1024);

  flash_attn<<<dim3(S_LEN / 64, Q_HEADS), 256, 0, stream>>>(Qbuf, KVbuf, Abuf);

  gemm_bt<<<dim3(D_MODEL / 64, S_LEN / 64), 256, 0, stream>>>(
      Abuf, W_out, b_out, out, S_LEN, D_MODEL, D_MODEL);
}

// Round 3
// 820.024 us; speedup vs baseline: 9.0039x; 1.8283x over previous
//
#include <hip/hip_runtime.h>
#include <hip/hip_bf16.h>
#include <math.h>

#define S_LEN 2048
#define D_MODEL 2048
#define Q_HEADS 32
#define KV_HEADS 8

typedef __attribute__((ext_vector_type(8))) short short8;   // 8 bf16 = 4 VGPRs
typedef __attribute__((ext_vector_type(4))) float f32x4;

// ---------------------------------------------------------------------------
// fp32 -> (hi, lo) bf16 split, RNE. hi+lo carries ~16 mantissa bits.
// ---------------------------------------------------------------------------
__device__ __forceinline__ short bf16_rne(float f) {
  unsigned u = __float_as_uint(f);
  unsigned r = (u + 0x7FFFu + ((u >> 16) & 1u)) >> 16;
  return (short)r;
}
__device__ __forceinline__ void f32_to_hl(float f, short& hi, short& lo) {
  hi = bf16_rne(f);
  float hf = __uint_as_float(((unsigned)(unsigned short)hi) << 16);
  lo = bf16_rne(f - hf);  // f - hf is exact in fp32
}

__global__ __launch_bounds__(256) void cvt_hl(const float* __restrict__ src,
                                              short* __restrict__ hi,
                                              short* __restrict__ lo, int n) {
  int i = (blockIdx.x * 256 + threadIdx.x) * 4;
  if (i >= n) return;
  float4 v = *(const float4*)&src[i];
  short4 h, l;
  f32_to_hl(v.x, h.x, l.x);
  f32_to_hl(v.y, h.y, l.y);
  f32_to_hl(v.z, h.z, l.z);
  f32_to_hl(v.w, h.w, l.w);
  *(short4*)&hi[i] = h;
  *(short4*)&lo[i] = l;
}

// ---------------------------------------------------------------------------
// Split-bf16 MFMA GEMM: C[m,n] = sum_k A[m,k]*B[n,k] + bias[n]
// A,B given as hi/lo bf16 pairs; C = Ah@Bh + Ah@Bl + Al@Bh (fp32 acc).
// BM=128, BN=64, BK=32; 256 threads = 4 waves, each wave 64x32 via 4x2 grid
// of mfma_f32_16x16x32_bf16. LDS stride 40 shorts (16B-aligned, 2-way free).
// Register-prefetch staging hides global latency under the MFMA section.
// ---------------------------------------------------------------------------
__global__ __launch_bounds__(256) void gemm_hl(
    const short* __restrict__ Ahi, const short* __restrict__ Alo,
    const short* __restrict__ Bhi, const short* __restrict__ Blo,
    const float* __restrict__ bias, float* __restrict__ C,
    int M, int N, int K) {
  constexpr int LK = 40;
  __shared__ short As_h[128 * LK], As_l[128 * LK];
  __shared__ short Bs_h[64 * LK], Bs_l[64 * LK];
  const int tid = threadIdx.x;
  const int bm = blockIdx.y * 128;
  const int bn = blockIdx.x * 64;
  const int w = tid >> 6, lane = tid & 63;
  const int l16 = lane & 15, quad = lane >> 4;
  const int wm = (w & 1) * 64, wn = (w >> 1) * 32;

  // staging coords: 16B chunks; A tile = 128 rows x 32 shorts (2 chunks/thr),
  // B tile = 64 rows x 32 shorts (1 chunk/thr)
  const int ra0 = tid >> 2, ca = (tid & 3) * 8;
  const int ra1 = ra0 + 64;
  const short* pAh0 = &Ahi[(size_t)(bm + ra0) * K + ca];
  const short* pAh1 = &Ahi[(size_t)(bm + ra1) * K + ca];
  const short* pAl0 = &Alo[(size_t)(bm + ra0) * K + ca];
  const short* pAl1 = &Alo[(size_t)(bm + ra1) * K + ca];
  const short* pBh  = &Bhi[(size_t)(bn + ra0) * K + ca];
  const short* pBl  = &Blo[(size_t)(bn + ra0) * K + ca];

  f32x4 acc[4][2];
#pragma unroll
  for (int i = 0; i < 4; ++i)
#pragma unroll
    for (int j = 0; j < 2; ++j)
#pragma unroll
      for (int e = 0; e < 4; ++e) acc[i][j][e] = 0.f;

  short8 gah0 = *(const short8*)pAh0;
  short8 gah1 = *(const short8*)pAh1;
  short8 gal0 = *(const short8*)pAl0;
  short8 gal1 = *(const short8*)pAl1;
  short8 gbh  = *(const short8*)pBh;
  short8 gbl  = *(const short8*)pBl;

  const int T = K / 32;
  for (int t = 0; t < T; ++t) {
    __syncthreads();                       // prior iteration's frag reads done
    *(short8*)&As_h[ra0 * LK + ca] = gah0;
    *(short8*)&As_h[ra1 * LK + ca] = gah1;
    *(short8*)&As_l[ra0 * LK + ca] = gal0;
    *(short8*)&As_l[ra1 * LK + ca] = gal1;
    *(short8*)&Bs_h[ra0 * LK + ca] = gbh;
    *(short8*)&Bs_l[ra0 * LK + ca] = gbl;
    __syncthreads();
    if (t + 1 < T) {                       // prefetch next tile into regs
      const int off = (t + 1) * 32;
      gah0 = *(const short8*)(pAh0 + off);
      gah1 = *(const short8*)(pAh1 + off);
      gal0 = *(const short8*)(pAl0 + off);
      gal1 = *(const short8*)(pAl1 + off);
      gbh  = *(const short8*)(pBh + off);
      gbl  = *(const short8*)(pBl + off);
    }
    short8 ah[4], al[4], bh[2], bl[2];
#pragma unroll
    for (int i = 0; i < 4; ++i) {
      ah[i] = *(const short8*)&As_h[(wm + i * 16 + l16) * LK + quad * 8];
      al[i] = *(const short8*)&As_l[(wm + i * 16 + l16) * LK + quad * 8];
    }
#pragma unroll
    for (int j = 0; j < 2; ++j) {
      bh[j] = *(const short8*)&Bs_h[(wn + j * 16 + l16) * LK + quad * 8];
      bl[j] = *(const short8*)&Bs_l[(wn + j * 16 + l16) * LK + quad * 8];
    }
#pragma unroll
    for (int i = 0; i < 4; ++i)
#pragma unroll
      for (int j = 0; j < 2; ++j) {
        acc[i][j] = __builtin_amdgcn_mfma_f32_16x16x32_bf16(ah[i], bh[j], acc[i][j], 0, 0, 0);
        acc[i][j] = __builtin_amdgcn_mfma_f32_16x16x32_bf16(ah[i], bl[j], acc[i][j], 0, 0, 0);
        acc[i][j] = __builtin_amdgcn_mfma_f32_16x16x32_bf16(al[i], bh[j], acc[i][j], 0, 0, 0);
      }
  }

  // epilogue: C/D layout col=lane&15, row=quad*4+reg
#pragma unroll
  for (int i = 0; i < 4; ++i) {
#pragma unroll
    for (int j = 0; j < 2; ++j) {
      const int col = bn + wn + j * 16 + l16;
      const float bv = bias[col];
      const int row0 = bm + wm + i * 16 + quad * 4;
#pragma unroll
      for (int e = 0; e < 4; ++e)
        C[(size_t)(row0 + e) * N + col] = acc[i][j][e] + bv;
    }
  }
}

// ---------------------------------------------------------------------------
// RoPE, interleaved pairs (double-precision angles).
// ---------------------------------------------------------------------------
__global__ void rope_kernel(float* __restrict__ X, int rowstride) {
  const int s = blockIdx.x;
  const int tid = threadIdx.x;
  const int h = tid >> 5;
  const int j = tid & 31;
  const double e = (2.0 * j) / 64.0;
  const double freq = pow(10000.0, -e);
  const double theta = (double)s * freq;
  double sd, cd;
  sincos(theta, &sd, &cd);
  const float cs = (float)cd, sn = (float)sd;
  float* p = &X[(long)s * rowstride + h * 64 + 2 * j];
  const float x1 = p[0], x2 = p[1];
  p[0] = x1 * cs - x2 * sn;
  p[1] = x1 * sn + x2 * cs;
}

// ---------------------------------------------------------------------------
// Flash attention, fp32 VALU. Grid (S/64, Q_HEADS), 256 threads.
// Epilogue writes hi/lo bf16 directly (feeds split-bf16 out-projection).
// ---------------------------------------------------------------------------
__global__ __launch_bounds__(256) void flash_attn(
    const float* __restrict__ Q, const float* __restrict__ KV,
    short* __restrict__ Ohi, short* __restrict__ Olo) {
  const int qt = blockIdx.x;
  const int h  = blockIdx.y;
  const int kvh = h >> 2;
  const int tid = threadIdx.x;
  const int tx = tid & 15;
  const int ty = tid >> 4;

  __shared__ float Qt[64][68];
  __shared__ float Kt[64][68];
  __shared__ float Vs[64][68];
  __shared__ float Ps[64][68];

  const int srow = tid >> 2;
  const int scol = (tid & 3) * 4;

  {
    const float* qg = &Q[(long)(qt * 64 + srow) * D_MODEL + h * 64];
#pragma unroll
    for (int c2 = 0; c2 < 4; ++c2) {
      const int c = scol + 16 * c2;
      float4 v = *(const float4*)&qg[c];
      Qt[c + 0][srow] = v.x * 0.125f;
      Qt[c + 1][srow] = v.y * 0.125f;
      Qt[c + 2][srow] = v.z * 0.125f;
      Qt[c + 3][srow] = v.w * 0.125f;
    }
  }

  float m[4], l[4], o[4][4];
#pragma unroll
  for (int i = 0; i < 4; ++i) {
    m[i] = -INFINITY; l[i] = 0.f;
#pragma unroll
    for (int j = 0; j < 4; ++j) o[i][j] = 0.f;
  }

  for (int t = 0; t < 32; ++t) {
    __syncthreads();
    {
      const float* kg = &KV[(long)(t * 64 + srow) * 1024 + kvh * 64];
#pragma unroll
      for (int c2 = 0; c2 < 4; ++c2) {
        const int c = scol + 16 * c2;
        float4 kv4 = *(const float4*)&kg[c];
        Kt[c + 0][srow] = kv4.x;
        Kt[c + 1][srow] = kv4.y;
        Kt[c + 2][srow] = kv4.z;
        Kt[c + 3][srow] = kv4.w;
        float4 vv4 = *(const float4*)&kg[512 + c];
        *(float4*)&Vs[srow][c] = vv4;
      }
    }
    __syncthreads();

    float s[4][4] = {};
#pragma unroll 8
    for (int k = 0; k < 64; ++k) {
      float4 qv = *(const float4*)&Qt[k][ty * 4];
      float4 kv = *(const float4*)&Kt[k][tx * 4];
      const float qa[4] = {qv.x, qv.y, qv.z, qv.w};
      const float kb[4] = {kv.x, kv.y, kv.z, kv.w};
#pragma unroll
      for (int i = 0; i < 4; ++i)
#pragma unroll
        for (int j = 0; j < 4; ++j) s[i][j] += qa[i] * kb[j];
    }

#pragma unroll
    for (int i = 0; i < 4; ++i) {
      float rm = fmaxf(fmaxf(s[i][0], s[i][1]), fmaxf(s[i][2], s[i][3]));
      rm = fmaxf(rm, __shfl_xor(rm, 1));
      rm = fmaxf(rm, __shfl_xor(rm, 2));
      rm = fmaxf(rm, __shfl_xor(rm, 4));
      rm = fmaxf(rm, __shfl_xor(rm, 8));
      const float mnew = fmaxf(m[i], rm);
      const float alpha = __expf(m[i] - mnew);
      float rs = 0.f;
#pragma unroll
      for (int j = 0; j < 4; ++j) {
        s[i][j] = __expf(s[i][j] - mnew);
        rs += s[i][j];
      }
      rs += __shfl_xor(rs, 1);
      rs += __shfl_xor(rs, 2);
      rs += __shfl_xor(rs, 4);
      rs += __shfl_xor(rs, 8);
      l[i] = l[i] * alpha + rs;
      m[i] = mnew;
#pragma unroll
      for (int j = 0; j < 4; ++j) o[i][j] *= alpha;
      *(float4*)&Ps[ty * 4 + i][tx * 4] =
          make_float4(s[i][0], s[i][1], s[i][2], s[i][3]);
    }
    __syncthreads();

#pragma unroll 4
    for (int k0 = 0; k0 < 64; k0 += 4) {
      float p[4][4], v[4][4];
#pragma unroll
      for (int i = 0; i < 4; ++i) {
        float4 t4 = *(const float4*)&Ps[ty * 4 + i][k0];
        p[i][0] = t4.x; p[i][1] = t4.y; p[i][2] = t4.z; p[i][3] = t4.w;
      }
#pragma unroll
      for (int kk = 0; kk < 4; ++kk) {
        float4 t4 = *(const float4*)&Vs[k0 + kk][tx * 4];
        v[kk][0] = t4.x; v[kk][1] = t4.y; v[kk][2] = t4.z; v[kk][3] = t4.w;
      }
#pragma unroll
      for (int i = 0; i < 4; ++i)
#pragma unroll
        for (int kk = 0; kk < 4; ++kk)
#pragma unroll
          for (int j = 0; j < 4; ++j) o[i][j] += p[i][kk] * v[kk][j];
    }
  }

#pragma unroll
  for (int i = 0; i < 4; ++i) {
    const float inv = 1.f / l[i];
    short4 h4, l4;
    f32_to_hl(o[i][0] * inv, h4.x, l4.x);
    f32_to_hl(o[i][1] * inv, h4.y, l4.y);
    f32_to_hl(o[i][2] * inv, h4.z, l4.z);
    f32_to_hl(o[i][3] * inv, h4.w, l4.w);
    const size_t base =
        (size_t)(qt * 64 + ty * 4 + i) * D_MODEL + h * 64 + tx * 4;
    *(short4*)&Ohi[base] = h4;
    *(short4*)&Olo[base] = l4;
  }
}

// ---------------------------------------------------------------------------
extern "C" void kernel_launch(void* const* d_in, const int* in_sizes, int n_in,
                              void* d_out, int out_size, void* d_ws, size_t ws_size,
                              hipStream_t stream) {
  const float* x     = (const float*)d_in[0];
  const float* W_q   = (const float*)d_in[1];
  const float* b_q   = (const float*)d_in[2];
  const float* W_kv  = (const float*)d_in[3];
  const float* b_kv  = (const float*)d_in[4];
  const float* W_out = (const float*)d_in[5];
  const float* b_out = (const float*)d_in[6];
  float* out = (float*)d_out;

  char* ws = (char*)d_ws;                       // 80 MB total
  float* Qbuf  = (float*)(ws);                  // 16 MB fp32 [2048,2048]
  float* KVbuf = (float*)(ws + (16u << 20));    //  8 MB fp32 [2048,1024]
  short* xhi   = (short*)(ws + (24u << 20));    //  8 MB
  short* xlo   = (short*)(ws + (32u << 20));    //  8 MB
  short* Wqh   = (short*)(ws + (40u << 20));    //  8 MB
  short* Wql   = (short*)(ws + (48u << 20));    //  8 MB
  short* Wkvh  = (short*)(ws + (56u << 20));    //  4 MB
  short* Wkvl  = (short*)(ws + (60u << 20));    //  4 MB
  short* Woh   = (short*)(ws + (64u << 20));    //  8 MB
  short* Wol   = (short*)(ws + (72u << 20));    //  8 MB
  // attn output hi/lo aliases x hi/lo (x dead after the two projections)
  short* Athi = xhi;
  short* Atlo = xlo;

  const int NM = 2048 * 2048;   // 4M elems
  const int NKV = 1024 * 2048;  // 2M elems
  cvt_hl<<<NM / 1024, 256, 0, stream>>>(x, xhi, xlo, NM);
  cvt_hl<<<NM / 1024, 256, 0, stream>>>(W_q, Wqh, Wql, NM);
  cvt_hl<<<NKV / 1024, 256, 0, stream>>>(W_kv, Wkvh, Wkvl, NKV);
  cvt_hl<<<NM / 1024, 256, 0, stream>>>(W_out, Woh, Wol, NM);

  // Q projection [2048,2048], KV projection [2048,1024]
  gemm_hl<<<dim3(2048 / 64, 2048 / 128), 256, 0, stream>>>(
      xhi, xlo, Wqh, Wql, b_q, Qbuf, 2048, 2048, 2048);
  gemm_hl<<<dim3(1024 / 64, 2048 / 128), 256, 0, stream>>>(
      xhi, xlo, Wkvh, Wkvl, b_kv, KVbuf, 2048, 1024, 2048);

  rope_kernel<<<S_LEN, Q_HEADS * 32, 0, stream>>>(Qbuf, D_MODEL);
  rope_kernel<<<S_LEN, KV_HEADS * 32, 0, stream>>>(KVbuf, 1024);

  flash_attn<<<dim3(S_LEN / 64, Q_HEADS), 256, 0, stream>>>(Qbuf, KVbuf, Athi, Atlo);

  // out projection
  gemm_hl<<<dim3(2048 / 64, 2048 / 128), 256, 0, stream>>>(
      Athi, Atlo, Woh, Wol, b_out, out, 2048, 2048, 2048);
}

// Round 4
// 428.645 us; speedup vs baseline: 17.2251x; 1.9131x over previous
//
#include <hip/hip_runtime.h>
#include <hip/hip_bf16.h>
#include <math.h>

#define S_LEN 2048
#define D_MODEL 2048
#define Q_HEADS 32
#define KV_HEADS 8

typedef __attribute__((ext_vector_type(8))) short short8;   // 8 bf16 = 4 VGPRs
typedef __attribute__((ext_vector_type(4))) float f32x4;

// ---------------------------------------------------------------------------
// fp32 -> bf16 RNE, and fp32 -> (hi,lo) bf16 split (~16 mantissa bits).
// ---------------------------------------------------------------------------
__device__ __forceinline__ short bf16_rne(float f) {
  unsigned u = __float_as_uint(f);
  unsigned r = (u + 0x7FFFu + ((u >> 16) & 1u)) >> 16;
  return (short)r;
}
__device__ __forceinline__ void f32_to_hl(float f, short& hi, short& lo) {
  hi = bf16_rne(f);
  float hf = __uint_as_float(((unsigned)(unsigned short)hi) << 16);
  lo = bf16_rne(f - hf);  // f - hf exact in fp32
}

__global__ __launch_bounds__(256) void cvt_hl(const float* __restrict__ src,
                                              short* __restrict__ hi,
                                              short* __restrict__ lo, int n) {
  int i = (blockIdx.x * 256 + threadIdx.x) * 4;
  if (i >= n) return;
  float4 v = *(const float4*)&src[i];
  short4 h, l;
  f32_to_hl(v.x, h.x, l.x);
  f32_to_hl(v.y, h.y, l.y);
  f32_to_hl(v.z, h.z, l.z);
  f32_to_hl(v.w, h.w, l.w);
  *(short4*)&hi[i] = h;
  *(short4*)&lo[i] = l;
}

// ---------------------------------------------------------------------------
// Split-bf16 MFMA GEMM (unchanged from round 3): C = A@B^T + bias,
// C = Ah@Bh + Ah@Bl + Al@Bh in fp32 AGPRs.
// ---------------------------------------------------------------------------
__global__ __launch_bounds__(256) void gemm_hl(
    const short* __restrict__ Ahi, const short* __restrict__ Alo,
    const short* __restrict__ Bhi, const short* __restrict__ Blo,
    const float* __restrict__ bias, float* __restrict__ C,
    int M, int N, int K) {
  constexpr int LK = 40;
  __shared__ short As_h[128 * LK], As_l[128 * LK];
  __shared__ short Bs_h[64 * LK], Bs_l[64 * LK];
  const int tid = threadIdx.x;
  const int bm = blockIdx.y * 128;
  const int bn = blockIdx.x * 64;
  const int w = tid >> 6, lane = tid & 63;
  const int l16 = lane & 15, quad = lane >> 4;
  const int wm = (w & 1) * 64, wn = (w >> 1) * 32;

  const int ra0 = tid >> 2, ca = (tid & 3) * 8;
  const int ra1 = ra0 + 64;
  const short* pAh0 = &Ahi[(size_t)(bm + ra0) * K + ca];
  const short* pAh1 = &Ahi[(size_t)(bm + ra1) * K + ca];
  const short* pAl0 = &Alo[(size_t)(bm + ra0) * K + ca];
  const short* pAl1 = &Alo[(size_t)(bm + ra1) * K + ca];
  const short* pBh  = &Bhi[(size_t)(bn + ra0) * K + ca];
  const short* pBl  = &Blo[(size_t)(bn + ra0) * K + ca];

  f32x4 acc[4][2];
#pragma unroll
  for (int i = 0; i < 4; ++i)
#pragma unroll
    for (int j = 0; j < 2; ++j)
#pragma unroll
      for (int e = 0; e < 4; ++e) acc[i][j][e] = 0.f;

  short8 gah0 = *(const short8*)pAh0;
  short8 gah1 = *(const short8*)pAh1;
  short8 gal0 = *(const short8*)pAl0;
  short8 gal1 = *(const short8*)pAl1;
  short8 gbh  = *(const short8*)pBh;
  short8 gbl  = *(const short8*)pBl;

  const int T = K / 32;
  for (int t = 0; t < T; ++t) {
    __syncthreads();
    *(short8*)&As_h[ra0 * LK + ca] = gah0;
    *(short8*)&As_h[ra1 * LK + ca] = gah1;
    *(short8*)&As_l[ra0 * LK + ca] = gal0;
    *(short8*)&As_l[ra1 * LK + ca] = gal1;
    *(short8*)&Bs_h[ra0 * LK + ca] = gbh;
    *(short8*)&Bs_l[ra0 * LK + ca] = gbl;
    __syncthreads();
    if (t + 1 < T) {
      const int off = (t + 1) * 32;
      gah0 = *(const short8*)(pAh0 + off);
      gah1 = *(const short8*)(pAh1 + off);
      gal0 = *(const short8*)(pAl0 + off);
      gal1 = *(const short8*)(pAl1 + off);
      gbh  = *(const short8*)(pBh + off);
      gbl  = *(const short8*)(pBl + off);
    }
    short8 ah[4], al[4], bh[2], bl[2];
#pragma unroll
    for (int i = 0; i < 4; ++i) {
      ah[i] = *(const short8*)&As_h[(wm + i * 16 + l16) * LK + quad * 8];
      al[i] = *(const short8*)&As_l[(wm + i * 16 + l16) * LK + quad * 8];
    }
#pragma unroll
    for (int j = 0; j < 2; ++j) {
      bh[j] = *(const short8*)&Bs_h[(wn + j * 16 + l16) * LK + quad * 8];
      bl[j] = *(const short8*)&Bs_l[(wn + j * 16 + l16) * LK + quad * 8];
    }
#pragma unroll
    for (int i = 0; i < 4; ++i)
#pragma unroll
      for (int j = 0; j < 2; ++j) {
        acc[i][j] = __builtin_amdgcn_mfma_f32_16x16x32_bf16(ah[i], bh[j], acc[i][j], 0, 0, 0);
        acc[i][j] = __builtin_amdgcn_mfma_f32_16x16x32_bf16(ah[i], bl[j], acc[i][j], 0, 0, 0);
        acc[i][j] = __builtin_amdgcn_mfma_f32_16x16x32_bf16(al[i], bh[j], acc[i][j], 0, 0, 0);
      }
  }

#pragma unroll
  for (int i = 0; i < 4; ++i) {
#pragma unroll
    for (int j = 0; j < 2; ++j) {
      const int col = bn + wn + j * 16 + l16;
      const float bv = bias[col];
      const int row0 = bm + wm + i * 16 + quad * 4;
#pragma unroll
      for (int e = 0; e < 4; ++e)
        C[(size_t)(row0 + e) * N + col] = acc[i][j][e] + bv;
    }
  }
}

// ---------------------------------------------------------------------------
// RoPE. theta computed with fp32 rounding (pos_f32 * freq_f32) to match the
// numpy fp32 reference's angle bits; trig evaluated in double on that angle.
// ---------------------------------------------------------------------------
__global__ void rope_kernel(float* __restrict__ X, int rowstride) {
  const int s = blockIdx.x;
  const int tid = threadIdx.x;
  const int h = tid >> 5;
  const int j = tid & 31;
  const double e = (2.0 * j) / 64.0;
  const float freq = (float)pow(10000.0, -e);   // correctly-rounded fp32 freq
  const float theta = (float)s * freq;          // fp32 product, RNE (matches np)
  double sd, cd;
  sincos((double)theta, &sd, &cd);
  const float cs = (float)cd, sn = (float)sd;
  float* p = &X[(long)s * rowstride + h * 64 + 2 * j];
  const float x1 = p[0], x2 = p[1];
  p[0] = x1 * cs - x2 * sn;
  p[1] = x1 * sn + x2 * cs;
}

// ---------------------------------------------------------------------------
// MFMA flash attention. Grid (S/64, Q_HEADS), 256 thr = 4 waves.
// Per block: 64 q-rows x one head; 32 K-tiles of 64 keys.
// S^T = K.Q^T  (A=K [key][d] natural, B=Q [q][d] natural, reg-resident)
//   -> C-layout: lane holds q=l16, keys=quad*4+e  => P written as b64 rows
// O^T = V^T.P^T (A=Vt [d][key], B=P from Ps[q][key] natural b128)
//   -> C-layout: lane holds q=l16, d=quad*4+e     => b64 global hi/lo write
// Ps rows are wave-private (each wave owns its 16 q rows).
// Softmax state per lane (its q), reduced across quads via shfl_xor 16/32.
// ---------------------------------------------------------------------------
#define LKS 72   // short stride (144 B, 16B-aligned, odd 16B-groups)

__global__ __launch_bounds__(256) void flash_attn_mfma(
    const float* __restrict__ Q, const float* __restrict__ KV,
    short* __restrict__ Ohi, short* __restrict__ Olo) {
  const int qt = blockIdx.x;
  const int h  = blockIdx.y;
  const int kvh = h >> 2;
  const int tid = threadIdx.x;
  const int w = tid >> 6;
  const int lane = tid & 63;
  const int l16 = lane & 15, quad = lane >> 4;

  __shared__ short Ks[64 * LKS];
  __shared__ short Vt[64 * LKS];
  __shared__ short Ps[64 * LKS];   // also Q staging area pre-loop

  // ---- stage Q tile as bf16 (prescaled by 1/8) into Ps, grab frags ----
  const int srow = tid >> 2, scol = (tid & 3) * 16;
  {
    const float* qg = &Q[(size_t)(qt * 64 + srow) * D_MODEL + h * 64 + scol];
    short tmp[16];
#pragma unroll
    for (int c = 0; c < 16; c += 4) {
      float4 v = *(const float4*)&qg[c];
      tmp[c + 0] = bf16_rne(v.x * 0.125f);
      tmp[c + 1] = bf16_rne(v.y * 0.125f);
      tmp[c + 2] = bf16_rne(v.z * 0.125f);
      tmp[c + 3] = bf16_rne(v.w * 0.125f);
    }
    *(short8*)&Ps[srow * LKS + scol]     = *(short8*)&tmp[0];
    *(short8*)&Ps[srow * LKS + scol + 8] = *(short8*)&tmp[8];
  }
  __syncthreads();
  short8 qf[2];
#pragma unroll
  for (int ks = 0; ks < 2; ++ks)
    qf[ks] = *(const short8*)&Ps[(w * 16 + l16) * LKS + ks * 32 + quad * 8];

  // V staging coords: 4x4 sub-blocks (keys vk.., d vd..)
  const int vk = (tid & 15) * 4, vd = (tid >> 4) * 4;

  float mm = -INFINITY, ll = 0.f;
  f32x4 acco[4];
#pragma unroll
  for (int m = 0; m < 4; ++m)
#pragma unroll
    for (int e = 0; e < 4; ++e) acco[m][e] = 0.f;

  for (int t = 0; t < 32; ++t) {
    __syncthreads();   // prior tile's Ks/Vt reads done (also covers Q-frag reads)
    // ---- stage K natural bf16 ----
    {
      const float* kg = &KV[(size_t)(t * 64 + srow) * 1024 + kvh * 64 + scol];
      short tmp[16];
#pragma unroll
      for (int c = 0; c < 16; c += 4) {
        float4 v = *(const float4*)&kg[c];
        tmp[c + 0] = bf16_rne(v.x);
        tmp[c + 1] = bf16_rne(v.y);
        tmp[c + 2] = bf16_rne(v.z);
        tmp[c + 3] = bf16_rne(v.w);
      }
      *(short8*)&Ks[srow * LKS + scol]     = *(short8*)&tmp[0];
      *(short8*)&Ks[srow * LKS + scol + 8] = *(short8*)&tmp[8];
    }
    // ---- stage V transposed (Vt[d][key]) via 4x4 blocks, b64 writes ----
    {
      float4 v4[4];
#pragma unroll
      for (int r = 0; r < 4; ++r)
        v4[r] = *(const float4*)&KV[(size_t)(t * 64 + vk + r) * 1024 + 512 + kvh * 64 + vd];
      const float* vf = (const float*)v4;   // vf[r*4+c]
#pragma unroll
      for (int c = 0; c < 4; ++c) {
        short4 s4;
        s4.x = bf16_rne(vf[0 * 4 + c]);
        s4.y = bf16_rne(vf[1 * 4 + c]);
        s4.z = bf16_rne(vf[2 * 4 + c]);
        s4.w = bf16_rne(vf[3 * 4 + c]);
        *(short4*)&Vt[(vd + c) * LKS + vk] = s4;
      }
    }
    __syncthreads();

    // ---- S^T = K.Q^T : 4 key-tiles x (d=64 -> 2 ksteps) ----
    f32x4 accs[4];
#pragma unroll
    for (int m = 0; m < 4; ++m)
#pragma unroll
      for (int e = 0; e < 4; ++e) accs[m][e] = 0.f;
#pragma unroll
    for (int m = 0; m < 4; ++m)
#pragma unroll
      for (int ks = 0; ks < 2; ++ks) {
        short8 kf = *(const short8*)&Ks[(m * 16 + l16) * LKS + ks * 32 + quad * 8];
        accs[m] = __builtin_amdgcn_mfma_f32_16x16x32_bf16(kf, qf[ks], accs[m], 0, 0, 0);
      }

    // ---- online softmax (per lane: its q = w*16+l16; keys quad*4+e per m) --
    float rm = -INFINITY;
#pragma unroll
    for (int m = 0; m < 4; ++m)
#pragma unroll
      for (int e = 0; e < 4; ++e) rm = fmaxf(rm, accs[m][e]);
    rm = fmaxf(rm, __shfl_xor(rm, 16));
    rm = fmaxf(rm, __shfl_xor(rm, 32));
    const float mnew = fmaxf(mm, rm);
    const float alpha = __expf(mm - mnew);
    float p[4][4];
    float rs = 0.f;
#pragma unroll
    for (int m = 0; m < 4; ++m)
#pragma unroll
      for (int e = 0; e < 4; ++e) {
        p[m][e] = __expf(accs[m][e] - mnew);
        rs += p[m][e];
      }
    rs += __shfl_xor(rs, 16);
    rs += __shfl_xor(rs, 32);
    ll = ll * alpha + rs;
    mm = mnew;
#pragma unroll
    for (int m = 0; m < 4; ++m)
#pragma unroll
      for (int e = 0; e < 4; ++e) acco[m][e] *= alpha;
    // write P (bf16) rows: Ps[q][key], 4 consecutive keys per b64
#pragma unroll
    for (int m = 0; m < 4; ++m) {
      short4 pk;
      pk.x = bf16_rne(p[m][0]);
      pk.y = bf16_rne(p[m][1]);
      pk.z = bf16_rne(p[m][2]);
      pk.w = bf16_rne(p[m][3]);
      *(short4*)&Ps[(w * 16 + l16) * LKS + m * 16 + quad * 4] = pk;
    }
    __syncthreads();   // cheap wave-RAW guard for Ps (wave-private rows)

    // ---- O^T += V^T.P^T : 4 d-tiles x (keys=64 -> 2 ksteps) ----
    short8 pf[2];
#pragma unroll
    for (int ks = 0; ks < 2; ++ks)
      pf[ks] = *(const short8*)&Ps[(w * 16 + l16) * LKS + ks * 32 + quad * 8];
#pragma unroll
    for (int m = 0; m < 4; ++m)
#pragma unroll
      for (int ks = 0; ks < 2; ++ks) {
        short8 vf = *(const short8*)&Vt[(m * 16 + l16) * LKS + ks * 32 + quad * 8];
        acco[m] = __builtin_amdgcn_mfma_f32_16x16x32_bf16(vf, pf[ks], acco[m], 0, 0, 0);
      }
  }

  // ---- epilogue: O^T lane holds q=l16(+w*16), d=quad*4+e per d-tile ----
  const float inv = 1.f / ll;
  const size_t qrow = (size_t)(qt * 64 + w * 16 + l16);
#pragma unroll
  for (int m = 0; m < 4; ++m) {
    short4 h4, l4;
    f32_to_hl(acco[m][0] * inv, h4.x, l4.x);
    f32_to_hl(acco[m][1] * inv, h4.y, l4.y);
    f32_to_hl(acco[m][2] * inv, h4.z, l4.z);
    f32_to_hl(acco[m][3] * inv, h4.w, l4.w);
    const size_t base = qrow * D_MODEL + h * 64 + m * 16 + quad * 4;
    *(short4*)&Ohi[base] = h4;
    *(short4*)&Olo[base] = l4;
  }
}

// ---------------------------------------------------------------------------
extern "C" void kernel_launch(void* const* d_in, const int* in_sizes, int n_in,
                              void* d_out, int out_size, void* d_ws, size_t ws_size,
                              hipStream_t stream) {
  const float* x     = (const float*)d_in[0];
  const float* W_q   = (const float*)d_in[1];
  const float* b_q   = (const float*)d_in[2];
  const float* W_kv  = (const float*)d_in[3];
  const float* b_kv  = (const float*)d_in[4];
  const float* W_out = (const float*)d_in[5];
  const float* b_out = (const float*)d_in[6];
  float* out = (float*)d_out;

  char* ws = (char*)d_ws;
  float* Qbuf  = (float*)(ws);                  // 16 MB fp32 [2048,2048]
  float* KVbuf = (float*)(ws + (16u << 20));    //  8 MB fp32 [2048,1024]
  short* xhi   = (short*)(ws + (24u << 20));
  short* xlo   = (short*)(ws + (32u << 20));
  short* Wqh   = (short*)(ws + (40u << 20));
  short* Wql   = (short*)(ws + (48u << 20));
  short* Wkvh  = (short*)(ws + (56u << 20));
  short* Wkvl  = (short*)(ws + (60u << 20));
  short* Woh   = (short*)(ws + (64u << 20));
  short* Wol   = (short*)(ws + (72u << 20));
  short* Athi = xhi;   // x dead after projections
  short* Atlo = xlo;

  const int NM = 2048 * 2048;
  const int NKV = 1024 * 2048;
  cvt_hl<<<NM / 1024, 256, 0, stream>>>(x, xhi, xlo, NM);
  cvt_hl<<<NM / 1024, 256, 0, stream>>>(W_q, Wqh, Wql, NM);
  cvt_hl<<<NKV / 1024, 256, 0, stream>>>(W_kv, Wkvh, Wkvl, NKV);
  cvt_hl<<<NM / 1024, 256, 0, stream>>>(W_out, Woh, Wol, NM);

  gemm_hl<<<dim3(2048 / 64, 2048 / 128), 256, 0, stream>>>(
      xhi, xlo, Wqh, Wql, b_q, Qbuf, 2048, 2048, 2048);
  gemm_hl<<<dim3(1024 / 64, 2048 / 128), 256, 0, stream>>>(
      xhi, xlo, Wkvh, Wkvl, b_kv, KVbuf, 2048, 1024, 2048);

  rope_kernel<<<S_LEN, Q_HEADS * 32, 0, stream>>>(Qbuf, D_MODEL);
  rope_kernel<<<S_LEN, KV_HEADS * 32, 0, stream>>>(KVbuf, 1024);

  flash_attn_mfma<<<dim3(S_LEN / 64, Q_HEADS), 256, 0, stream>>>(
      Qbuf, KVbuf, Athi, Atlo);

  gemm_hl<<<dim3(2048 / 64, 2048 / 128), 256, 0, stream>>>(
      Athi, Atlo, Woh, Wol, b_out, out, 2048, 2048, 2048);
}